// Round 8
// baseline (207.373 us; speedup 1.0000x reference)
//
#include <hip/hip_runtime.h>
#include <math.h>

typedef unsigned short u16;
typedef _Float16 f16;
typedef __attribute__((ext_vector_type(8))) short bf16x8;
typedef __attribute__((ext_vector_type(4))) float f32x4;

__device__ __forceinline__ float sigf(float x) { return 1.0f / (1.0f + expf(-x)); }
__device__ __forceinline__ u16 f2bf(float f) {
    unsigned x = __float_as_uint(f);
    return (u16)((x + 0x7fffu + ((x >> 16) & 1u)) >> 16);
}

// sorted insert, ascending by (d, idx) — matches jax.lax.top_k stable tie-break.
#define INS4(D, J) do {                                                              \
    float _d = (D); int _j = (J);                                                    \
    if (_d < bd3 || (_d == bd3 && _j < bj3)) {                                       \
        bd3 = _d; bj3 = _j;                                                          \
        if (bd3 < bd2 || (bd3 == bd2 && bj3 < bj2)) {                                \
            float _t = bd2; bd2 = bd3; bd3 = _t; int _u = bj2; bj2 = bj3; bj3 = _u; }\
        if (bd2 < bd1 || (bd2 == bd1 && bj2 < bj1)) {                                \
            float _t = bd1; bd1 = bd2; bd2 = _t; int _u = bj1; bj1 = bj2; bj2 = _u; }\
        if (bd1 < bd0 || (bd1 == bd0 && bj1 < bj0)) {                                \
            float _t = bd0; bd0 = bd1; bd1 = _t; int _u = bj0; bj0 = bj1; bj1 = _u; }\
    } } while (0)

__global__ void diag_kernel(float* out, int code, int out_size) {
    if (out_size > 0) out[0] = (float)code * 1.0e8f;
}

// Prep: bf16 weights pre-shuffled into MFMA B-fragment order so that in-kernel
// B loads are 64 lanes x 16 B contiguous (fully coalesced).
//   Wgf[((gt*9 + kt)*64 + lane)*8 + j] = W[gt*16 + (lane&15)][kt*32 + (lane>>4)*8 + j]
//   where W[g][k] = (k<32 ? Wih[g][k] : Whh[g][k-32]),  gt 0..63, kt 0..8.
//   Wpf[((pt*8 + kt)*64 + lane)*8 + j] = Wp[pt*16 + (lane&15)][kt*32 + (lane>>4)*8 + j]
__global__ __launch_bounds__(256) void prep_frag(
    const float* __restrict__ Wih, const float* __restrict__ Whh,
    const float* __restrict__ Wp,
    u16* __restrict__ Wgf, u16* __restrict__ Wpf)
{
    int id = blockIdx.x * 256 + threadIdx.x;
    if (id < 36864) {                        // gates: 64 gt * 9 kt * 64 lanes
        int gt = id / 576, rem = id - gt * 576;
        int kt = rem >> 6, lane = rem & 63;
        int g  = gt * 16 + (lane & 15);
        int k  = kt * 32 + (lane >> 4) * 8;
        u16* dst = Wgf + (size_t)id * 8;
        #pragma unroll
        for (int j = 0; j < 8; j++) {
            int kk = k + j;
            float v = (kk < 32) ? Wih[(size_t)g * 32 + kk]
                                : Whh[(size_t)g * 256 + (kk - 32)];
            dst[j] = f2bf(v);
        }
    } else if (id < 36864 + 1024) {          // pool: 2 pt * 8 kt * 64 lanes
        int id2 = id - 36864;
        int pt = id2 >> 9, rem = id2 & 511;
        int kt = rem >> 6, lane = rem & 63;
        int o  = pt * 16 + (lane & 15);
        int k  = kt * 32 + (lane >> 4) * 8;
        u16* dst = Wpf + (size_t)id2 * 8;
        #pragma unroll
        for (int j = 0; j < 8; j++)
            dst[j] = f2bf(Wp[(size_t)o * 256 + k + j]);
    }
}

// Main fused kernel. Block = 256 threads = 16 pedestrians.
// LDS 42,816 B -> 3 blocks/CU.
//   [0, 9472):      sXb u16[16][296]  X=[emb|h] bf16   (reused as sHb u16[16][264])
//   [9472, 42816):  union:
//     merge:  sMd f32[16][65] (4160) | sMj i32[16][65] (4160)
//     gates:  gbuf f16[16][1042] (33,344)
__global__ __launch_bounds__(256) void nnlstm_mfma(
    const float* __restrict__ obs1, const float* __restrict__ obs2,
    const float* __restrict__ h,    const float* __restrict__ c,
    const float* __restrict__ Wemb, const float* __restrict__ bemb,
    const u16*  __restrict__ Wgf,   const float* __restrict__ bih,
    const float* __restrict__ bhh,
    const u16*  __restrict__ Wpf,   const float* __restrict__ bp,
    int n, float* __restrict__ out)
{
    __shared__ __align__(16) char lds[42816];
    u16*  sXb = (u16*)lds;                    // [16][296] bf16
    char* uni = lds + 9472;
    float* sMd = (float*)uni;                 // [16][65]
    int*   sMj = (int*)(uni + 4160);          // [16][65]
    f16*   gbuf = (f16*)uni;                  // [16][1042]
    u16*   sHb = (u16*)lds;                   // [16][264] bf16 h_new (overlays sXb)

    const int t    = threadIdx.x;
    const int sub  = t & 15;
    const int ii   = t >> 4;
    const int i0   = blockIdx.x * 16;
    const int i    = i0 + ii;
    const int lane = t & 63;
    const int wv   = t >> 6;          // wave 0..3
    const int fm   = lane & 15;       // MFMA m/n index
    const int fq   = lane >> 4;       // MFMA k-quad

    // ---- stage h -> sXb[:,32:288] as bf16 (coalesced float4 reads) ----
    for (int f = t; f < 16 * 64; f += 256) {
        int r = f >> 6, k4 = f & 63;
        int row = i0 + r;
        float4 hv = (row < n) ? ((const float4*)h)[(size_t)row * 64 + k4]
                              : make_float4(0.f, 0.f, 0.f, 0.f);
        u16* d = &sXb[r * 296 + 32 + k4 * 4];
        d[0] = f2bf(hv.x); d[1] = f2bf(hv.y); d[2] = f2bf(hv.z); d[3] = f2bf(hv.w);
    }

    // ---- Phase A: per-lane strided top-4 scan, obs2 direct from global ----
    // All 4 ped-groups in a wave read the same j -> 2-line broadcast loads, L1-hot.
    float bd0 = 1e30f, bd1 = 1e30f, bd2 = 1e30f, bd3 = 1e30f;
    int   bj0 = 0x7fffffff, bj1 = 0x7fffffff, bj2 = 0x7fffffff, bj3 = 0x7fffffff;

    if (i < n) {
        const float2* o2 = (const float2*)obs2;
        const float2 pi = o2[i];
        const float inf = __builtin_inff();
        int j = sub;
        for (; j + 48 < n; j += 64) {                 // 4 loads in flight
            float2 p0 = o2[j], p1 = o2[j + 16], p2 = o2[j + 32], p3 = o2[j + 48];
            float dx, dy, d2, dd;
            dx = p0.x - pi.x; dy = p0.y - pi.y;
            d2 = __fadd_rn(__fmul_rn(dx, dx), __fmul_rn(dy, dy));
            dd = (j == i) ? inf : __fsqrt_rn(d2);            INS4(dd, j);
            dx = p1.x - pi.x; dy = p1.y - pi.y;
            d2 = __fadd_rn(__fmul_rn(dx, dx), __fmul_rn(dy, dy));
            dd = (j + 16 == i) ? inf : __fsqrt_rn(d2);       INS4(dd, j + 16);
            dx = p2.x - pi.x; dy = p2.y - pi.y;
            d2 = __fadd_rn(__fmul_rn(dx, dx), __fmul_rn(dy, dy));
            dd = (j + 32 == i) ? inf : __fsqrt_rn(d2);       INS4(dd, j + 32);
            dx = p3.x - pi.x; dy = p3.y - pi.y;
            d2 = __fadd_rn(__fmul_rn(dx, dx), __fmul_rn(dy, dy));
            dd = (j + 48 == i) ? inf : __fsqrt_rn(d2);       INS4(dd, j + 48);
        }
        for (; j < n; j += 16) {
            float2 pj = o2[j];
            float dx = pj.x - pi.x, dy = pj.y - pi.y;
            float d2 = __fadd_rn(__fmul_rn(dx, dx), __fmul_rn(dy, dy));
            float dd = (j == i) ? inf : __fsqrt_rn(d2);
            INS4(dd, j);
        }
    }
    sMd[ii * 65 + sub * 4 + 0] = bd0;  sMj[ii * 65 + sub * 4 + 0] = bj0;
    sMd[ii * 65 + sub * 4 + 1] = bd1;  sMj[ii * 65 + sub * 4 + 1] = bj1;
    sMd[ii * 65 + sub * 4 + 2] = bd2;  sMj[ii * 65 + sub * 4 + 2] = bj2;
    sMd[ii * 65 + sub * 4 + 3] = bd3;  sMj[ii * 65 + sub * 4 + 3] = bj3;
    __syncthreads();   // B2

    // ---- merge (t<16: thread r = pedestrian r) + Linear(4,8)+ReLU -> sXb[:,0:32) ----
    if (t < 16) {
        const int r = t;
        const int irow = i0 + r;
        float bd0 = 1e30f, bd1 = 1e30f, bd2 = 1e30f, bd3 = 1e30f;
        int   bj0 = 0x7fffffff, bj1 = 0x7fffffff, bj2 = 0x7fffffff, bj3 = 0x7fffffff;
        for (int q = 0; q < 64; q++) { INS4(sMd[r * 65 + q], sMj[r * 65 + q]); }

        if (irow < n) {
            float pix = obs2[2 * irow], piy = obs2[2 * irow + 1];
            float vix = pix - obs1[2 * irow];
            float viy = piy - obs1[2 * irow + 1];
            #pragma unroll
            for (int q2 = 0; q2 < 4; q2++) {
                int jn = (q2 == 0) ? bj0 : (q2 == 1) ? bj1 : (q2 == 2) ? bj2 : bj3;
                if (jn < 0 || jn >= n) jn = 0;   // safety clamp
                float pjx = obs2[2 * jn], pjy = obs2[2 * jn + 1];
                float px = pjx - pix, py = pjy - piy;
                float vx = (pjx - obs1[2 * jn])     - vix;
                float vy = (pjy - obs1[2 * jn + 1]) - viy;
                #pragma unroll
                for (int e = 0; e < 8; e++) {
                    float a = px * Wemb[e]      + py * Wemb[8 + e]
                            + vx * Wemb[16 + e] + vy * Wemb[24 + e]
                            + bemb[e];
                    sXb[r * 296 + q2 * 8 + e] = f2bf(fmaxf(a, 0.0f));
                }
            }
        } else {
            for (int e = 0; e < 32; e++) sXb[r * 296 + e] = 0;
        }
    }
    __syncthreads();   // B3 (sMd/sMj dead; gbuf region free)

    // ---- Phase B: gates GEMM via MFMA; wave wv covers gates [wv*256, wv*256+256) ----
    bf16x8 afr[9];
    #pragma unroll
    for (int kt = 0; kt < 9; kt++)
        afr[kt] = *(const bf16x8*)&sXb[fm * 296 + kt * 32 + fq * 8];

    for (int nt = 0; nt < 16; nt++) {
        const int gt = wv * 16 + nt;
        const u16* wbase = Wgf + ((size_t)gt * 9) * 512 + lane * 8;
        f32x4 acc = {0.f, 0.f, 0.f, 0.f};
        #pragma unroll
        for (int kt = 0; kt < 9; kt++) {
            bf16x8 bfr = *(const bf16x8*)(wbase + kt * 512);   // coalesced 1 KB/wave
            acc = __builtin_amdgcn_mfma_f32_16x16x32_bf16(afr[kt], bfr, acc, 0, 0, 0);
        }
        // D: col = fm (gate gt*16+fm), rows fq*4 + reg
        #pragma unroll
        for (int r_ = 0; r_ < 4; r_++)
            gbuf[(fq * 4 + r_) * 1042 + gt * 16 + fm] = (f16)acc[r_];
    }
    __syncthreads();   // B4

    // ---- LSTM pointwise (gate order i,f,g,o); thread t = hidden unit u ----
    {
        const int u = t;
        float b0 = bih[u]       + bhh[u];
        float b1 = bih[u + 256] + bhh[u + 256];
        float b2 = bih[u + 512] + bhh[u + 512];
        float b3 = bih[u + 768] + bhh[u + 768];
        for (int r = 0; r < 16; r++) {
            int row = i0 + r;
            float cin = (row < n) ? c[(size_t)row * 256 + u] : 0.0f;
            float gi = (float)gbuf[r * 1042 + u]       + b0;
            float gf = (float)gbuf[r * 1042 + u + 256] + b1;
            float gg = (float)gbuf[r * 1042 + u + 512] + b2;
            float go = (float)gbuf[r * 1042 + u + 768] + b3;
            float cn = sigf(gf) * cin + sigf(gi) * tanhf(gg);
            float hn = sigf(go) * tanhf(cn);
            sHb[r * 264 + u] = f2bf(hn);
        }
    }
    __syncthreads();   // B5

    // ---- Pool GEMM via MFMA: M=16 x N=32 x K=256; waves 0,1 one n-tile each ----
    if (wv < 2) {
        bf16x8 ah[8];
        #pragma unroll
        for (int kt = 0; kt < 8; kt++)
            ah[kt] = *(const bf16x8*)&sHb[fm * 264 + kt * 32 + fq * 8];
        const u16* wbase = Wpf + ((size_t)wv * 8) * 512 + lane * 8;
        f32x4 acc = {0.f, 0.f, 0.f, 0.f};
        #pragma unroll
        for (int kt = 0; kt < 8; kt++) {
            bf16x8 bfr = *(const bf16x8*)(wbase + kt * 512);
            acc = __builtin_amdgcn_mfma_f32_16x16x32_bf16(ah[kt], bfr, acc, 0, 0, 0);
        }
        float bias = bp[wv * 16 + fm];
        #pragma unroll
        for (int r_ = 0; r_ < 4; r_++) {
            int row = i0 + fq * 4 + r_;
            if (row < n) out[(size_t)row * 32 + wv * 16 + fm] = acc[r_] + bias;
        }
    }
}

// ---- proven round-5 fallback (only if ws too small) ----
__global__ __launch_bounds__(256) void nnlstm_fallback(
    const float* __restrict__ obs1, const float* __restrict__ obs2,
    const float* __restrict__ h,    const float* __restrict__ c,
    const float* __restrict__ Wemb, const float* __restrict__ bemb,
    const float* __restrict__ Wih,  const float* __restrict__ bih,
    const float* __restrict__ Whh,  const float* __restrict__ bhh,
    const float* __restrict__ Wp,   const float* __restrict__ bp,
    int n, float* __restrict__ out)
{
    __shared__ float sMd[16][64];
    __shared__ int   sMj[16][64];
    __shared__ float sX[16][292];
    __shared__ float sH[16][264];

    const int t   = threadIdx.x;
    const int sub = t & 15;
    const int ii  = t >> 4;
    const int i0  = blockIdx.x * 16;
    const int i   = i0 + ii;

    for (int v = t; v < 16 * 256; v += 256) {
        int r = v >> 8, k = v & 255;
        int row = i0 + r;
        sX[r][32 + k] = (row < n) ? h[(size_t)row * 256 + k] : 0.0f;
    }

    float bd0 = 1e30f, bd1 = 1e30f, bd2 = 1e30f, bd3 = 1e30f;
    int   bj0 = 0x7fffffff, bj1 = 0x7fffffff, bj2 = 0x7fffffff, bj3 = 0x7fffffff;

    if (i < n) {
        const float pix = obs2[2 * i];
        const float piy = obs2[2 * i + 1];
        for (int j = sub; j < n; j += 16) {
            float dx = obs2[2 * j]     - pix;
            float dy = obs2[2 * j + 1] - piy;
            float d2 = __fadd_rn(__fmul_rn(dx, dx), __fmul_rn(dy, dy));
            float dist = __fsqrt_rn(d2);
            if (j == i) continue;
            INS4(dist, j);
        }
    }
    sMd[ii][sub * 4 + 0] = bd0;  sMj[ii][sub * 4 + 0] = bj0;
    sMd[ii][sub * 4 + 1] = bd1;  sMj[ii][sub * 4 + 1] = bj1;
    sMd[ii][sub * 4 + 2] = bd2;  sMj[ii][sub * 4 + 2] = bj2;
    sMd[ii][sub * 4 + 3] = bd3;  sMj[ii][sub * 4 + 3] = bj3;
    __syncthreads();

    if (t < 16) {
        const int r = t;
        const int irow = i0 + r;
        float bd0 = 1e30f, bd1 = 1e30f, bd2 = 1e30f, bd3 = 1e30f;
        int   bj0 = 0x7fffffff, bj1 = 0x7fffffff, bj2 = 0x7fffffff, bj3 = 0x7fffffff;
        for (int q = 0; q < 64; q++) { INS4(sMd[r][q], sMj[r][q]); }

        if (irow < n) {
            float pix = obs2[2 * irow], piy = obs2[2 * irow + 1];
            float vix = pix - obs1[2 * irow];
            float viy = piy - obs1[2 * irow + 1];
            #pragma unroll
            for (int q2 = 0; q2 < 4; q2++) {
                int jn = (q2 == 0) ? bj0 : (q2 == 1) ? bj1 : (q2 == 2) ? bj2 : bj3;
                if (jn < 0 || jn >= n) jn = 0;
                float pjx = obs2[2 * jn], pjy = obs2[2 * jn + 1];
                float px = pjx - pix, py = pjy - piy;
                float vx = (pjx - obs1[2 * jn])     - vix;
                float vy = (pjy - obs1[2 * jn + 1]) - viy;
                #pragma unroll
                for (int e = 0; e < 8; e++) {
                    float a = px * Wemb[e]      + py * Wemb[8 + e]
                            + vx * Wemb[16 + e] + vy * Wemb[24 + e]
                            + bemb[e];
                    sX[r][q2 * 8 + e] = fmaxf(a, 0.0f);
                }
            }
        } else {
            for (int e = 0; e < 32; e++) sX[r][e] = 0.0f;
        }
    }
    __syncthreads();

    const int uu = t;
    float acc[4][16];
    #pragma unroll
    for (int j = 0; j < 4; j++) {
        float b = bih[uu + 256 * j] + bhh[uu + 256 * j];
        #pragma unroll
        for (int r = 0; r < 16; r++) acc[j][r] = b;
    }

    for (int kc = 0; kc < 288; kc++) {
        float w[4];
        #pragma unroll
        for (int j = 0; j < 4; j++) {
            int g = uu + 256 * j;
            w[j] = (kc < 32) ? Wih[(size_t)g * 32 + kc]
                             : Whh[(size_t)g * 256 + (kc - 32)];
        }
        #pragma unroll
        for (int r = 0; r < 16; r++) {
            float x = sX[r][kc];
            #pragma unroll
            for (int j = 0; j < 4; j++) acc[j][r] += w[j] * x;
        }
    }

    for (int r = 0; r < 16; r++) {
        int row = i0 + r;
        float cin = (row < n) ? c[(size_t)row * 256 + uu] : 0.0f;
        float cn = sigf(acc[1][r]) * cin + sigf(acc[0][r]) * tanhf(acc[2][r]);
        float hn = sigf(acc[3][r]) * tanhf(cn);
        sH[r][uu] = hn;
    }
    __syncthreads();

    for (int v = t; v < 16 * 32; v += 256) {
        int r = v >> 5, o = v & 31;
        int row = i0 + r;
        if (row >= n) continue;
        float a = bp[o];
        for (int kc = 0; kc < 256; kc++)
            a += Wp[(size_t)o * 256 + kc] * sH[r][kc];
        out[(size_t)row * 32 + o] = a;
    }
}

extern "C" void kernel_launch(void* const* d_in, const int* in_sizes, int n_in,
                              void* d_out, int out_size, void* d_ws, size_t ws_size,
                              hipStream_t stream) {
    float* out = (float*)d_out;

    int code = 0, n = 0;
    if (n_in != 12) code = 1;
    else {
        n = in_sizes[1] / 2;
        if (n <= 4 || in_sizes[1] != 2 * n)          code = 2;
        else if (in_sizes[0]  != 2 * n)              code = 3;
        else if (in_sizes[2]  != 256 * n)            code = 4;
        else if (in_sizes[3]  != 256 * n)            code = 5;
        else if (in_sizes[4]  != 32 || in_sizes[5] != 8)        code = 6;
        else if (in_sizes[6]  != 32768 || in_sizes[7] != 1024)  code = 7;
        else if (in_sizes[8]  != 262144 || in_sizes[9] != 1024) code = 8;
        else if (in_sizes[10] != 8192 || in_sizes[11] != 32)    code = 9;
        else if (out_size != 32 * n)                 code = 10;
    }
    if (code != 0) {
        diag_kernel<<<1, 1, 0, stream>>>(out, code, out_size);
        return;
    }

    const float* obs1   = (const float*)d_in[0];
    const float* obs2   = (const float*)d_in[1];
    const float* h      = (const float*)d_in[2];
    const float* c      = (const float*)d_in[3];
    const float* W_emb  = (const float*)d_in[4];
    const float* b_emb  = (const float*)d_in[5];
    const float* W_ih   = (const float*)d_in[6];
    const float* b_ih   = (const float*)d_in[7];
    const float* W_hh   = (const float*)d_in[8];
    const float* b_hh   = (const float*)d_in[9];
    const float* W_pool = (const float*)d_in[10];
    const float* b_pool = (const float*)d_in[11];

    int grid = (n + 15) / 16;
    const size_t wgf_bytes = (size_t)36864 * 8 * sizeof(u16);   // 589,824
    const size_t wpf_bytes = (size_t)1024 * 8 * sizeof(u16);    //  16,384

    if (ws_size >= wgf_bytes + wpf_bytes) {
        u16* Wgf = (u16*)d_ws;
        u16* Wpf = (u16*)((char*)d_ws + wgf_bytes);
        prep_frag<<<(36864 + 1024 + 255) / 256, 256, 0, stream>>>(
            W_ih, W_hh, W_pool, Wgf, Wpf);
        nnlstm_mfma<<<grid, 256, 0, stream>>>(
            obs1, obs2, h, c, W_emb, b_emb, Wgf, b_ih, b_hh, Wpf, b_pool, n, out);
    } else {
        nnlstm_fallback<<<grid, 256, 0, stream>>>(
            obs1, obs2, h, c, W_emb, b_emb, W_ih, b_ih, W_hh, b_hh,
            W_pool, b_pool, n, out);
    }
}

// Round 9
// 190.404 us; speedup vs baseline: 1.0891x; 1.0891x over previous
//
#include <hip/hip_runtime.h>
#include <math.h>

typedef unsigned short u16;
typedef _Float16 f16;
typedef __attribute__((ext_vector_type(8))) short bf16x8;
typedef __attribute__((ext_vector_type(4))) float f32x4;

__device__ __forceinline__ float sigf(float x) { return 1.0f / (1.0f + expf(-x)); }
__device__ __forceinline__ u16 f2bf(float f) {
    unsigned x = __float_as_uint(f);
    return (u16)((x + 0x7fffu + ((x >> 16) & 1u)) >> 16);
}

// sorted insert, ascending by (d, idx) — matches jax.lax.top_k stable tie-break.
#define INS4(D, J) do {                                                              \
    float _d = (D); int _j = (J);                                                    \
    if (_d < bd3 || (_d == bd3 && _j < bj3)) {                                       \
        bd3 = _d; bj3 = _j;                                                          \
        if (bd3 < bd2 || (bd3 == bd2 && bj3 < bj2)) {                                \
            float _t = bd2; bd2 = bd3; bd3 = _t; int _u = bj2; bj2 = bj3; bj3 = _u; }\
        if (bd2 < bd1 || (bd2 == bd1 && bj2 < bj1)) {                                \
            float _t = bd1; bd1 = bd2; bd2 = _t; int _u = bj1; bj1 = bj2; bj2 = _u; }\
        if (bd1 < bd0 || (bd1 == bd0 && bj1 < bj0)) {                                \
            float _t = bd0; bd0 = bd1; bd1 = _t; int _u = bj0; bj0 = bj1; bj1 = _u; }\
    } } while (0)

__global__ void diag_kernel(float* out, int code, int out_size) {
    if (out_size > 0) out[0] = (float)code * 1.0e8f;
}

// K1: blocks [0, knn_blocks): kNN top-4 + Linear(4,8)+ReLU emb -> out (fp32, [n,32]).
//     One WAVE per pedestrian (64 lanes scan n/64 candidates each, shfl butterfly).
//     blocks [knn_blocks, knn_blocks+148): bf16 weight prep into MFMA-fragment order:
//       Wgf[((gt*9+kt)*64+lane)*8+j] = W[gt*16+(lane&15)][kt*32+(lane>>4)*8+j]
//       Wpf analogous for W_pool.
__global__ __launch_bounds__(256) void knn_prep_kernel(
    const float* __restrict__ obs1, const float* __restrict__ obs2,
    const float* __restrict__ Wemb, const float* __restrict__ bemb,
    const float* __restrict__ Wih,  const float* __restrict__ Whh,
    const float* __restrict__ Wp,
    u16* __restrict__ Wgf, u16* __restrict__ Wpf,
    int n, int knn_blocks, float* __restrict__ out)
{
    const int t = threadIdx.x;

    if (blockIdx.x >= knn_blocks) {
        // ---- prep portion ----
        int id = (blockIdx.x - knn_blocks) * 256 + t;
        if (id < 36864) {                        // gates: 64 gt * 9 kt * 64 lanes
            int gt = id / 576, rem = id - gt * 576;
            int kt = rem >> 6, ln = rem & 63;
            int g  = gt * 16 + (ln & 15);
            int k  = kt * 32 + (ln >> 4) * 8;
            u16* dst = Wgf + (size_t)id * 8;
            #pragma unroll
            for (int j = 0; j < 8; j++) {
                int kk = k + j;
                float v = (kk < 32) ? Wih[(size_t)g * 32 + kk]
                                    : Whh[(size_t)g * 256 + (kk - 32)];
                dst[j] = f2bf(v);
            }
        } else if (id < 37888) {                 // pool: 2 pt * 8 kt * 64 lanes
            int id2 = id - 36864;
            int pt = id2 >> 9, rem = id2 & 511;
            int kt = rem >> 6, ln = rem & 63;
            int o  = pt * 16 + (ln & 15);
            int k  = kt * 32 + (ln >> 4) * 8;
            u16* dst = Wpf + (size_t)id2 * 8;
            #pragma unroll
            for (int j = 0; j < 8; j++)
                dst[j] = f2bf(Wp[(size_t)o * 256 + k + j]);
        }
        return;
    }

    // ---- kNN portion: wave wv handles pedestrian i ----
    const int lane = t & 63;
    const int wv   = t >> 6;
    const int i    = blockIdx.x * 4 + wv;
    if (i >= n) return;                          // wave-uniform exit, no barriers in K1

    const float2* o2 = (const float2*)obs2;
    const float2 pi = o2[i];
    const float inf = __builtin_inff();

    float bd0 = 1e30f, bd1 = 1e30f, bd2 = 1e30f, bd3 = 1e30f;
    int   bj0 = 0x7fffffff, bj1 = 0x7fffffff, bj2 = 0x7fffffff, bj3 = 0x7fffffff;

    int j = lane;
    for (; j + 192 < n; j += 256) {              // 4 coalesced 512B wave-loads in flight
        float2 p0 = o2[j], p1 = o2[j + 64], p2 = o2[j + 128], p3 = o2[j + 192];
        float dx, dy, d2, dd;
        dx = p0.x - pi.x; dy = p0.y - pi.y;
        d2 = __fadd_rn(__fmul_rn(dx, dx), __fmul_rn(dy, dy));
        dd = (j == i) ? inf : __fsqrt_rn(d2);             INS4(dd, j);
        dx = p1.x - pi.x; dy = p1.y - pi.y;
        d2 = __fadd_rn(__fmul_rn(dx, dx), __fmul_rn(dy, dy));
        dd = (j + 64 == i) ? inf : __fsqrt_rn(d2);        INS4(dd, j + 64);
        dx = p2.x - pi.x; dy = p2.y - pi.y;
        d2 = __fadd_rn(__fmul_rn(dx, dx), __fmul_rn(dy, dy));
        dd = (j + 128 == i) ? inf : __fsqrt_rn(d2);       INS4(dd, j + 128);
        dx = p3.x - pi.x; dy = p3.y - pi.y;
        d2 = __fadd_rn(__fmul_rn(dx, dx), __fmul_rn(dy, dy));
        dd = (j + 192 == i) ? inf : __fsqrt_rn(d2);       INS4(dd, j + 192);
    }
    for (; j < n; j += 64) {
        float2 pj = o2[j];
        float dx = pj.x - pi.x, dy = pj.y - pi.y;
        float d2 = __fadd_rn(__fmul_rn(dx, dx), __fmul_rn(dy, dy));
        float dd = (j == i) ? inf : __fsqrt_rn(d2);
        INS4(dd, j);
    }

    // butterfly merge across 64 lanes: exact top-4 under (d, idx) total order
    #pragma unroll
    for (int m = 1; m < 64; m <<= 1) {
        float od0 = __shfl_xor(bd0, m), od1 = __shfl_xor(bd1, m);
        float od2 = __shfl_xor(bd2, m), od3 = __shfl_xor(bd3, m);
        int   oj0 = __shfl_xor(bj0, m), oj1 = __shfl_xor(bj1, m);
        int   oj2 = __shfl_xor(bj2, m), oj3 = __shfl_xor(bj3, m);
        INS4(od0, oj0); INS4(od1, oj1); INS4(od2, oj2); INS4(od3, oj3);
    }

    if (lane < 4) {   // lane q emits neighbour q's 8 embedding dims (fp32) into out
        int jn = (lane == 0) ? bj0 : (lane == 1) ? bj1 : (lane == 2) ? bj2 : bj3;
        if (jn < 0 || jn >= n) jn = 0;           // safety clamp
        float pix = pi.x, piy = pi.y;
        float pjx = obs2[2 * jn], pjy = obs2[2 * jn + 1];
        float px = pjx - pix, py = pjy - piy;
        float vix = pix - obs1[2 * i];
        float viy = piy - obs1[2 * i + 1];
        float vx = (pjx - obs1[2 * jn])     - vix;
        float vy = (pjy - obs1[2 * jn + 1]) - viy;
        float* dst = out + (size_t)i * 32 + lane * 8;
        #pragma unroll
        for (int e = 0; e < 8; e++) {
            float a = px * Wemb[e]      + py * Wemb[8 + e]
                    + vx * Wemb[16 + e] + vy * Wemb[24 + e]
                    + bemb[e];
            dst[e] = fmaxf(a, 0.0f);
        }
    }
}

// K2: gates GEMM (MFMA) + LSTM + pool (MFMA). Block = 16 pedestrians.
// Reads emb (fp32) from out rows i0..i0+15, overwrites same rows at the end.
// LDS 42,816 B: sXb u16[16][296] | gbuf f16[16][1042] (sHb overlays sXb).
__global__ __launch_bounds__(256) void lstm_kernel(
    const float* __restrict__ h,   const float* __restrict__ c,
    const u16*  __restrict__ Wgf,  const float* __restrict__ bih,
    const float* __restrict__ bhh,
    const u16*  __restrict__ Wpf,  const float* __restrict__ bp,
    int n, float* __restrict__ out)
{
    __shared__ __align__(16) char lds[42816];
    u16* sXb  = (u16*)lds;                    // [16][296] bf16 X=[emb|h]
    f16* gbuf = (f16*)(lds + 9472);           // [16][1042]
    u16* sHb  = (u16*)lds;                    // [16][264] bf16 h_new (overlays sXb)

    const int t    = threadIdx.x;
    const int i0   = blockIdx.x * 16;
    const int lane = t & 63;
    const int wv   = t >> 6;
    const int fm   = lane & 15;
    const int fq   = lane >> 4;

    // stage emb (fp32 in out) -> sXb[:,0:32) bf16
    if (t < 128) {
        int r = t >> 3, k4 = (t & 7) * 4;
        int row = i0 + r;
        float4 ev = (row < n) ? ((const float4*)out)[(size_t)row * 8 + (k4 >> 2)]
                              : make_float4(0.f, 0.f, 0.f, 0.f);
        u16* d = &sXb[r * 296 + k4];
        d[0] = f2bf(ev.x); d[1] = f2bf(ev.y); d[2] = f2bf(ev.z); d[3] = f2bf(ev.w);
    }
    // stage h -> sXb[:,32:288) bf16
    for (int f = t; f < 16 * 64; f += 256) {
        int r = f >> 6, k4 = f & 63;
        int row = i0 + r;
        float4 hv = (row < n) ? ((const float4*)h)[(size_t)row * 64 + k4]
                              : make_float4(0.f, 0.f, 0.f, 0.f);
        u16* d = &sXb[r * 296 + 32 + k4 * 4];
        d[0] = f2bf(hv.x); d[1] = f2bf(hv.y); d[2] = f2bf(hv.z); d[3] = f2bf(hv.w);
    }
    __syncthreads();

    // gates GEMM via MFMA; wave wv covers gates [wv*256, wv*256+256)
    bf16x8 afr[9];
    #pragma unroll
    for (int kt = 0; kt < 9; kt++)
        afr[kt] = *(const bf16x8*)&sXb[fm * 296 + kt * 32 + fq * 8];

    for (int nt = 0; nt < 16; nt++) {
        const int gt = wv * 16 + nt;
        const u16* wbase = Wgf + ((size_t)gt * 9) * 512 + lane * 8;
        f32x4 acc = {0.f, 0.f, 0.f, 0.f};
        #pragma unroll
        for (int kt = 0; kt < 9; kt++) {
            bf16x8 bfr = *(const bf16x8*)(wbase + kt * 512);   // coalesced 1 KB/wave
            acc = __builtin_amdgcn_mfma_f32_16x16x32_bf16(afr[kt], bfr, acc, 0, 0, 0);
        }
        #pragma unroll
        for (int r_ = 0; r_ < 4; r_++)
            gbuf[(fq * 4 + r_) * 1042 + gt * 16 + fm] = (f16)acc[r_];
    }
    __syncthreads();

    // LSTM pointwise (gate order i,f,g,o); thread t = hidden unit u
    {
        const int u = t;
        float b0 = bih[u]       + bhh[u];
        float b1 = bih[u + 256] + bhh[u + 256];
        float b2 = bih[u + 512] + bhh[u + 512];
        float b3 = bih[u + 768] + bhh[u + 768];
        for (int r = 0; r < 16; r++) {
            int row = i0 + r;
            float cin = (row < n) ? c[(size_t)row * 256 + u] : 0.0f;
            float gi = (float)gbuf[r * 1042 + u]       + b0;
            float gf = (float)gbuf[r * 1042 + u + 256] + b1;
            float gg = (float)gbuf[r * 1042 + u + 512] + b2;
            float go = (float)gbuf[r * 1042 + u + 768] + b3;
            float cn = sigf(gf) * cin + sigf(gi) * tanhf(gg);
            float hn = sigf(go) * tanhf(cn);
            sHb[r * 264 + u] = f2bf(hn);
        }
    }
    __syncthreads();

    // pool GEMM via MFMA: M=16 x N=32 x K=256; waves 0,1 one n-tile each
    if (wv < 2) {
        bf16x8 ah[8];
        #pragma unroll
        for (int kt = 0; kt < 8; kt++)
            ah[kt] = *(const bf16x8*)&sHb[fm * 264 + kt * 32 + fq * 8];
        const u16* wbase = Wpf + ((size_t)wv * 8) * 512 + lane * 8;
        f32x4 acc = {0.f, 0.f, 0.f, 0.f};
        #pragma unroll
        for (int kt = 0; kt < 8; kt++) {
            bf16x8 bfr = *(const bf16x8*)(wbase + kt * 512);
            acc = __builtin_amdgcn_mfma_f32_16x16x32_bf16(ah[kt], bfr, acc, 0, 0, 0);
        }
        float bias = bp[wv * 16 + fm];
        #pragma unroll
        for (int r_ = 0; r_ < 4; r_++) {
            int row = i0 + fq * 4 + r_;
            if (row < n) out[(size_t)row * 32 + wv * 16 + fm] = acc[r_] + bias;
        }
    }
}

// ---- proven round-5 fallback (only if ws too small) ----
__global__ __launch_bounds__(256) void nnlstm_fallback(
    const float* __restrict__ obs1, const float* __restrict__ obs2,
    const float* __restrict__ h,    const float* __restrict__ c,
    const float* __restrict__ Wemb, const float* __restrict__ bemb,
    const float* __restrict__ Wih,  const float* __restrict__ bih,
    const float* __restrict__ Whh,  const float* __restrict__ bhh,
    const float* __restrict__ Wp,   const float* __restrict__ bp,
    int n, float* __restrict__ out)
{
    __shared__ float sMd[16][64];
    __shared__ int   sMj[16][64];
    __shared__ float sX[16][292];
    __shared__ float sH[16][264];

    const int t   = threadIdx.x;
    const int sub = t & 15;
    const int ii  = t >> 4;
    const int i0  = blockIdx.x * 16;
    const int i   = i0 + ii;

    for (int v = t; v < 16 * 256; v += 256) {
        int r = v >> 8, k = v & 255;
        int row = i0 + r;
        sX[r][32 + k] = (row < n) ? h[(size_t)row * 256 + k] : 0.0f;
    }

    float bd0 = 1e30f, bd1 = 1e30f, bd2 = 1e30f, bd3 = 1e30f;
    int   bj0 = 0x7fffffff, bj1 = 0x7fffffff, bj2 = 0x7fffffff, bj3 = 0x7fffffff;

    if (i < n) {
        const float pix = obs2[2 * i];
        const float piy = obs2[2 * i + 1];
        for (int j = sub; j < n; j += 16) {
            float dx = obs2[2 * j]     - pix;
            float dy = obs2[2 * j + 1] - piy;
            float d2 = __fadd_rn(__fmul_rn(dx, dx), __fmul_rn(dy, dy));
            float dist = __fsqrt_rn(d2);
            if (j == i) continue;
            INS4(dist, j);
        }
    }
    sMd[ii][sub * 4 + 0] = bd0;  sMj[ii][sub * 4 + 0] = bj0;
    sMd[ii][sub * 4 + 1] = bd1;  sMj[ii][sub * 4 + 1] = bj1;
    sMd[ii][sub * 4 + 2] = bd2;  sMj[ii][sub * 4 + 2] = bj2;
    sMd[ii][sub * 4 + 3] = bd3;  sMj[ii][sub * 4 + 3] = bj3;
    __syncthreads();

    if (t < 16) {
        const int r = t;
        const int irow = i0 + r;
        float bd0 = 1e30f, bd1 = 1e30f, bd2 = 1e30f, bd3 = 1e30f;
        int   bj0 = 0x7fffffff, bj1 = 0x7fffffff, bj2 = 0x7fffffff, bj3 = 0x7fffffff;
        for (int q = 0; q < 64; q++) { INS4(sMd[r][q], sMj[r][q]); }

        if (irow < n) {
            float pix = obs2[2 * irow], piy = obs2[2 * irow + 1];
            float vix = pix - obs1[2 * irow];
            float viy = piy - obs1[2 * irow + 1];
            #pragma unroll
            for (int q2 = 0; q2 < 4; q2++) {
                int jn = (q2 == 0) ? bj0 : (q2 == 1) ? bj1 : (q2 == 2) ? bj2 : bj3;
                if (jn < 0 || jn >= n) jn = 0;
                float pjx = obs2[2 * jn], pjy = obs2[2 * jn + 1];
                float px = pjx - pix, py = pjy - piy;
                float vx = (pjx - obs1[2 * jn])     - vix;
                float vy = (pjy - obs1[2 * jn + 1]) - viy;
                #pragma unroll
                for (int e = 0; e < 8; e++) {
                    float a = px * Wemb[e]      + py * Wemb[8 + e]
                            + vx * Wemb[16 + e] + vy * Wemb[24 + e]
                            + bemb[e];
                    sX[r][q2 * 8 + e] = fmaxf(a, 0.0f);
                }
            }
        } else {
            for (int e = 0; e < 32; e++) sX[r][e] = 0.0f;
        }
    }
    __syncthreads();

    const int uu = t;
    float acc[4][16];
    #pragma unroll
    for (int j = 0; j < 4; j++) {
        float b = bih[uu + 256 * j] + bhh[uu + 256 * j];
        #pragma unroll
        for (int r = 0; r < 16; r++) acc[j][r] = b;
    }

    for (int kc = 0; kc < 288; kc++) {
        float w[4];
        #pragma unroll
        for (int j = 0; j < 4; j++) {
            int g = uu + 256 * j;
            w[j] = (kc < 32) ? Wih[(size_t)g * 32 + kc]
                             : Whh[(size_t)g * 256 + (kc - 32)];
        }
        #pragma unroll
        for (int r = 0; r < 16; r++) {
            float x = sX[r][kc];
            #pragma unroll
            for (int j = 0; j < 4; j++) acc[j][r] += w[j] * x;
        }
    }

    for (int r = 0; r < 16; r++) {
        int row = i0 + r;
        float cin = (row < n) ? c[(size_t)row * 256 + uu] : 0.0f;
        float cn = sigf(acc[1][r]) * cin + sigf(acc[0][r]) * tanhf(acc[2][r]);
        float hn = sigf(acc[3][r]) * tanhf(cn);
        sH[r][uu] = hn;
    }
    __syncthreads();

    for (int v = t; v < 16 * 32; v += 256) {
        int r = v >> 5, o = v & 31;
        int row = i0 + r;
        if (row >= n) continue;
        float a = bp[o];
        for (int kc = 0; kc < 256; kc++)
            a += Wp[(size_t)o * 256 + kc] * sH[r][kc];
        out[(size_t)row * 32 + o] = a;
    }
}

extern "C" void kernel_launch(void* const* d_in, const int* in_sizes, int n_in,
                              void* d_out, int out_size, void* d_ws, size_t ws_size,
                              hipStream_t stream) {
    float* out = (float*)d_out;

    int code = 0, n = 0;
    if (n_in != 12) code = 1;
    else {
        n = in_sizes[1] / 2;
        if (n <= 4 || in_sizes[1] != 2 * n)          code = 2;
        else if (in_sizes[0]  != 2 * n)              code = 3;
        else if (in_sizes[2]  != 256 * n)            code = 4;
        else if (in_sizes[3]  != 256 * n)            code = 5;
        else if (in_sizes[4]  != 32 || in_sizes[5] != 8)        code = 6;
        else if (in_sizes[6]  != 32768 || in_sizes[7] != 1024)  code = 7;
        else if (in_sizes[8]  != 262144 || in_sizes[9] != 1024) code = 8;
        else if (in_sizes[10] != 8192 || in_sizes[11] != 32)    code = 9;
        else if (out_size != 32 * n)                 code = 10;
    }
    if (code != 0) {
        diag_kernel<<<1, 1, 0, stream>>>(out, code, out_size);
        return;
    }

    const float* obs1   = (const float*)d_in[0];
    const float* obs2   = (const float*)d_in[1];
    const float* h      = (const float*)d_in[2];
    const float* c      = (const float*)d_in[3];
    const float* W_emb  = (const float*)d_in[4];
    const float* b_emb  = (const float*)d_in[5];
    const float* W_ih   = (const float*)d_in[6];
    const float* b_ih   = (const float*)d_in[7];
    const float* W_hh   = (const float*)d_in[8];
    const float* b_hh   = (const float*)d_in[9];
    const float* W_pool = (const float*)d_in[10];
    const float* b_pool = (const float*)d_in[11];

    const size_t wgf_bytes = (size_t)36864 * 8 * sizeof(u16);   // 589,824
    const size_t wpf_bytes = (size_t)1024 * 8 * sizeof(u16);    //  16,384

    if (ws_size >= wgf_bytes + wpf_bytes) {
        u16* Wgf = (u16*)d_ws;
        u16* Wpf = (u16*)((char*)d_ws + wgf_bytes);
        int knn_blocks = (n + 3) / 4;
        knn_prep_kernel<<<knn_blocks + 148, 256, 0, stream>>>(
            obs1, obs2, W_emb, b_emb, W_ih, W_hh, W_pool, Wgf, Wpf,
            n, knn_blocks, out);
        lstm_kernel<<<(n + 15) / 16, 256, 0, stream>>>(
            h, c, Wgf, b_ih, b_hh, Wpf, b_pool, n, out);
    } else {
        nnlstm_fallback<<<(n + 15) / 16, 256, 0, stream>>>(
            obs1, obs2, h, c, W_emb, b_emb, W_ih, b_ih, W_hh, b_hh,
            W_pool, b_pool, n, out);
    }
}

// Round 10
// 159.007 us; speedup vs baseline: 1.3042x; 1.1975x over previous
//
#include <hip/hip_runtime.h>
#include <math.h>

typedef unsigned short u16;
typedef unsigned long long u64;
typedef _Float16 f16;
typedef __attribute__((ext_vector_type(8))) short bf16x8;
typedef __attribute__((ext_vector_type(4))) float f32x4;

__device__ __forceinline__ float sigf(float x)  { return 1.0f / (1.0f + __expf(-x)); }
__device__ __forceinline__ float tanhf_(float x){ float e = __expf(2.0f * x); return 1.0f - 2.0f / (e + 1.0f); }
__device__ __forceinline__ u16 f2bf(float f) {
    unsigned x = __float_as_uint(f);
    return (u16)((x + 0x7fffu + ((x >> 16) & 1u)) >> 16);
}

// u64-key sorted insert: keys k0<=k1<=k2<=k3, key = (asuint(dist)<<24)|idx.
// Single u64 compare == lexicographic (dist, idx) — exactly jax.lax.top_k order.
#define INSU(KEY) do {                                                              \
    u64 _k = (KEY);                                                                 \
    k3 = (_k < k3) ? _k : k3;                                                       \
    { bool _c = k3 < k2; u64 _lo = _c ? k3 : k2, _hi = _c ? k2 : k3; k2 = _lo; k3 = _hi; } \
    { bool _c = k2 < k1; u64 _lo = _c ? k2 : k1, _hi = _c ? k1 : k2; k1 = _lo; k2 = _hi; } \
    { bool _c = k1 < k0; u64 _lo = _c ? k1 : k0, _hi = _c ? k0 : k1; k0 = _lo; k1 = _hi; } \
} while (0)

// float-key variant for the fallback kernel (round-5 proven path)
#define INS4(D, J) do {                                                              \
    float _d = (D); int _j = (J);                                                    \
    if (_d < bd3 || (_d == bd3 && _j < bj3)) {                                       \
        bd3 = _d; bj3 = _j;                                                          \
        if (bd3 < bd2 || (bd3 == bd2 && bj3 < bj2)) {                                \
            float _t = bd2; bd2 = bd3; bd3 = _t; int _u = bj2; bj2 = bj3; bj3 = _u; }\
        if (bd2 < bd1 || (bd2 == bd1 && bj2 < bj1)) {                                \
            float _t = bd1; bd1 = bd2; bd2 = _t; int _u = bj1; bj1 = bj2; bj2 = _u; }\
        if (bd1 < bd0 || (bd1 == bd0 && bj1 < bj0)) {                                \
            float _t = bd0; bd0 = bd1; bd1 = _t; int _u = bj0; bj0 = bj1; bj1 = _u; }\
    } } while (0)

__global__ void diag_kernel(float* out, int code, int out_size) {
    if (out_size > 0) out[0] = (float)code * 1.0e8f;
}

// K1: blocks [0, knn_blocks): kNN top-4 + Linear(4,8)+ReLU emb -> out (fp32 [n,32]).
//     One WAVE per pedestrian; u64 packed keys; shfl-xor butterfly merge.
//     blocks [knn_blocks, ...): bf16 weight prep into MFMA B-fragment order.
__global__ __launch_bounds__(256) void knn_prep_kernel(
    const float* __restrict__ obs1, const float* __restrict__ obs2,
    const float* __restrict__ Wemb, const float* __restrict__ bemb,
    const float* __restrict__ Wih,  const float* __restrict__ Whh,
    const float* __restrict__ Wp,
    u16* __restrict__ Wgf, u16* __restrict__ Wpf,
    int n, int knn_blocks, float* __restrict__ out)
{
    const int t = threadIdx.x;

    if (blockIdx.x >= knn_blocks) {
        // ---- prep portion ----
        int id = (blockIdx.x - knn_blocks) * 256 + t;
        if (id < 36864) {                        // gates: 64 gt * 9 kt * 64 lanes
            int gt = id / 576, rem = id - gt * 576;
            int kt = rem >> 6, ln = rem & 63;
            int g  = gt * 16 + (ln & 15);
            int k  = kt * 32 + (ln >> 4) * 8;
            u16* dst = Wgf + (size_t)id * 8;
            #pragma unroll
            for (int j = 0; j < 8; j++) {
                int kk = k + j;
                float v = (kk < 32) ? Wih[(size_t)g * 32 + kk]
                                    : Whh[(size_t)g * 256 + (kk - 32)];
                dst[j] = f2bf(v);
            }
        } else if (id < 37888) {                 // pool: 2 pt * 8 kt * 64 lanes
            int id2 = id - 36864;
            int pt = id2 >> 9, rem = id2 & 511;
            int kt = rem >> 6, ln = rem & 63;
            int o  = pt * 16 + (ln & 15);
            int k  = kt * 32 + (ln >> 4) * 8;
            u16* dst = Wpf + (size_t)id2 * 8;
            #pragma unroll
            for (int j = 0; j < 8; j++)
                dst[j] = f2bf(Wp[(size_t)o * 256 + k + j]);
        }
        return;
    }

    // ---- kNN portion: wave handles pedestrian i ----
    const int lane = t & 63;
    const int wv   = t >> 6;
    const int i    = blockIdx.x * 4 + wv;
    if (i >= n) return;                          // wave-uniform exit

    const float2* o2 = (const float2*)obs2;
    const float2 pi = o2[i];

    u64 k0 = ~0ull, k1 = ~0ull, k2 = ~0ull, k3 = ~0ull;

    int j = lane;
    for (; j + 192 < n; j += 256) {              // 4 coalesced 512B wave-loads in flight
        float2 p0 = o2[j], p1 = o2[j + 64], p2 = o2[j + 128], p3 = o2[j + 192];
        float dx, dy, d2, dd; u64 key;
        dx = p0.x - pi.x; dy = p0.y - pi.y;
        d2 = __fadd_rn(__fmul_rn(dx, dx), __fmul_rn(dy, dy));
        dd = __fsqrt_rn(d2);
        key = (((u64)__float_as_uint(dd)) << 24) | (unsigned)j;
        key = (j == i) ? ~0ull : key;                         INSU(key);
        dx = p1.x - pi.x; dy = p1.y - pi.y;
        d2 = __fadd_rn(__fmul_rn(dx, dx), __fmul_rn(dy, dy));
        dd = __fsqrt_rn(d2);
        key = (((u64)__float_as_uint(dd)) << 24) | (unsigned)(j + 64);
        key = (j + 64 == i) ? ~0ull : key;                    INSU(key);
        dx = p2.x - pi.x; dy = p2.y - pi.y;
        d2 = __fadd_rn(__fmul_rn(dx, dx), __fmul_rn(dy, dy));
        dd = __fsqrt_rn(d2);
        key = (((u64)__float_as_uint(dd)) << 24) | (unsigned)(j + 128);
        key = (j + 128 == i) ? ~0ull : key;                   INSU(key);
        dx = p3.x - pi.x; dy = p3.y - pi.y;
        d2 = __fadd_rn(__fmul_rn(dx, dx), __fmul_rn(dy, dy));
        dd = __fsqrt_rn(d2);
        key = (((u64)__float_as_uint(dd)) << 24) | (unsigned)(j + 192);
        key = (j + 192 == i) ? ~0ull : key;                   INSU(key);
    }
    for (; j < n; j += 64) {
        float2 pj = o2[j];
        float dx = pj.x - pi.x, dy = pj.y - pi.y;
        float d2 = __fadd_rn(__fmul_rn(dx, dx), __fmul_rn(dy, dy));
        float dd = __fsqrt_rn(d2);
        u64 key = (((u64)__float_as_uint(dd)) << 24) | (unsigned)j;
        key = (j == i) ? ~0ull : key;
        INSU(key);
    }

    // butterfly merge across 64 lanes: exact top-4 under the u64 total order
    #pragma unroll
    for (int m = 1; m < 64; m <<= 1) {
        u64 o0 = __shfl_xor(k0, m), o1 = __shfl_xor(k1, m);
        u64 o2_ = __shfl_xor(k2, m), o3 = __shfl_xor(k3, m);
        INSU(o0); INSU(o1); INSU(o2_); INSU(o3);
    }

    if (lane < 4) {   // lane q emits neighbour q's 8 embedding dims (fp32) into out
        u64 kq = (lane == 0) ? k0 : (lane == 1) ? k1 : (lane == 2) ? k2 : k3;
        int jn = (int)(kq & 0xFFFFFF);
        if (jn < 0 || jn >= n) jn = 0;           // safety clamp (sentinel case)
        float pix = pi.x, piy = pi.y;
        float pjx = obs2[2 * jn], pjy = obs2[2 * jn + 1];
        float px = pjx - pix, py = pjy - piy;
        float vix = pix - obs1[2 * i];
        float viy = piy - obs1[2 * i + 1];
        float vx = (pjx - obs1[2 * jn])     - vix;
        float vy = (pjy - obs1[2 * jn + 1]) - viy;
        float* dst = out + (size_t)i * 32 + lane * 8;
        #pragma unroll
        for (int e = 0; e < 8; e++) {
            float a = px * Wemb[e]      + py * Wemb[8 + e]
                    + vx * Wemb[16 + e] + vy * Wemb[24 + e]
                    + bemb[e];
            dst[e] = fmaxf(a, 0.0f);
        }
    }
}

// K2: gates GEMM (MFMA) + LSTM + pool (MFMA). Block = 16 pedestrians.
// Reads emb (fp32) from out rows i0..i0+15, overwrites same rows at the end.
__global__ __launch_bounds__(256) void lstm_kernel(
    const float* __restrict__ h,   const float* __restrict__ c,
    const u16*  __restrict__ Wgf,  const float* __restrict__ bih,
    const float* __restrict__ bhh,
    const u16*  __restrict__ Wpf,  const float* __restrict__ bp,
    int n, float* __restrict__ out)
{
    __shared__ __align__(16) char lds[42816];
    u16* sXb  = (u16*)lds;                    // [16][296] bf16 X=[emb|h]
    f16* gbuf = (f16*)(lds + 9472);           // [16][1042]
    u16* sHb  = (u16*)lds;                    // [16][264] bf16 h_new (overlays sXb)

    const int t    = threadIdx.x;
    const int i0   = blockIdx.x * 16;
    const int lane = t & 63;
    const int wv   = t >> 6;
    const int fm   = lane & 15;
    const int fq   = lane >> 4;

    // stage emb (fp32 in out) -> sXb[:,0:32) bf16
    if (t < 128) {
        int r = t >> 3, k4 = (t & 7) * 4;
        int row = i0 + r;
        float4 ev = (row < n) ? ((const float4*)out)[(size_t)row * 8 + (k4 >> 2)]
                              : make_float4(0.f, 0.f, 0.f, 0.f);
        u16* d = &sXb[r * 296 + k4];
        d[0] = f2bf(ev.x); d[1] = f2bf(ev.y); d[2] = f2bf(ev.z); d[3] = f2bf(ev.w);
    }
    // stage h -> sXb[:,32:288) bf16
    for (int f = t; f < 16 * 64; f += 256) {
        int r = f >> 6, k4 = f & 63;
        int row = i0 + r;
        float4 hv = (row < n) ? ((const float4*)h)[(size_t)row * 64 + k4]
                              : make_float4(0.f, 0.f, 0.f, 0.f);
        u16* d = &sXb[r * 296 + 32 + k4 * 4];
        d[0] = f2bf(hv.x); d[1] = f2bf(hv.y); d[2] = f2bf(hv.z); d[3] = f2bf(hv.w);
    }
    __syncthreads();

    // gates GEMM via MFMA; wave wv covers gates [wv*256, wv*256+256)
    bf16x8 afr[9];
    #pragma unroll
    for (int kt = 0; kt < 9; kt++)
        afr[kt] = *(const bf16x8*)&sXb[fm * 296 + kt * 32 + fq * 8];

    #pragma unroll 2
    for (int nt = 0; nt < 16; nt++) {
        const int gt = wv * 16 + nt;
        const u16* wbase = Wgf + ((size_t)gt * 9) * 512 + lane * 8;
        f32x4 acc = {0.f, 0.f, 0.f, 0.f};
        #pragma unroll
        for (int kt = 0; kt < 9; kt++) {
            bf16x8 bfr = *(const bf16x8*)(wbase + kt * 512);   // coalesced 1 KB/wave
            acc = __builtin_amdgcn_mfma_f32_16x16x32_bf16(afr[kt], bfr, acc, 0, 0, 0);
        }
        #pragma unroll
        for (int r_ = 0; r_ < 4; r_++)
            gbuf[(fq * 4 + r_) * 1042 + gt * 16 + fm] = (f16)acc[r_];
    }
    __syncthreads();

    // LSTM pointwise (gate order i,f,g,o); thread t = hidden unit u
    {
        const int u = t;
        float b0 = bih[u]       + bhh[u];
        float b1 = bih[u + 256] + bhh[u + 256];
        float b2 = bih[u + 512] + bhh[u + 512];
        float b3 = bih[u + 768] + bhh[u + 768];
        for (int r = 0; r < 16; r++) {
            int row = i0 + r;
            float cin = (row < n) ? c[(size_t)row * 256 + u] : 0.0f;
            float gi = (float)gbuf[r * 1042 + u]       + b0;
            float gf = (float)gbuf[r * 1042 + u + 256] + b1;
            float gg = (float)gbuf[r * 1042 + u + 512] + b2;
            float go = (float)gbuf[r * 1042 + u + 768] + b3;
            float cn = sigf(gf) * cin + sigf(gi) * tanhf_(gg);
            float hn = sigf(go) * tanhf_(cn);
            sHb[r * 264 + u] = f2bf(hn);
        }
    }
    __syncthreads();

    // pool GEMM via MFMA: M=16 x N=32 x K=256; waves 0,1 one n-tile each
    if (wv < 2) {
        bf16x8 ah[8];
        #pragma unroll
        for (int kt = 0; kt < 8; kt++)
            ah[kt] = *(const bf16x8*)&sHb[fm * 264 + kt * 32 + fq * 8];
        const u16* wbase = Wpf + ((size_t)wv * 8) * 512 + lane * 8;
        f32x4 acc = {0.f, 0.f, 0.f, 0.f};
        #pragma unroll
        for (int kt = 0; kt < 8; kt++) {
            bf16x8 bfr = *(const bf16x8*)(wbase + kt * 512);
            acc = __builtin_amdgcn_mfma_f32_16x16x32_bf16(ah[kt], bfr, acc, 0, 0, 0);
        }
        float bias = bp[wv * 16 + fm];
        #pragma unroll
        for (int r_ = 0; r_ < 4; r_++) {
            int row = i0 + fq * 4 + r_;
            if (row < n) out[(size_t)row * 32 + wv * 16 + fm] = acc[r_] + bias;
        }
    }
}

// ---- proven round-5 fallback (only if ws too small) ----
__global__ __launch_bounds__(256) void nnlstm_fallback(
    const float* __restrict__ obs1, const float* __restrict__ obs2,
    const float* __restrict__ h,    const float* __restrict__ c,
    const float* __restrict__ Wemb, const float* __restrict__ bemb,
    const float* __restrict__ Wih,  const float* __restrict__ bih,
    const float* __restrict__ Whh,  const float* __restrict__ bhh,
    const float* __restrict__ Wp,   const float* __restrict__ bp,
    int n, float* __restrict__ out)
{
    __shared__ float sMd[16][64];
    __shared__ int   sMj[16][64];
    __shared__ float sX[16][292];
    __shared__ float sH[16][264];

    const int t   = threadIdx.x;
    const int sub = t & 15;
    const int ii  = t >> 4;
    const int i0  = blockIdx.x * 16;
    const int i   = i0 + ii;

    for (int v = t; v < 16 * 256; v += 256) {
        int r = v >> 8, k = v & 255;
        int row = i0 + r;
        sX[r][32 + k] = (row < n) ? h[(size_t)row * 256 + k] : 0.0f;
    }

    float bd0 = 1e30f, bd1 = 1e30f, bd2 = 1e30f, bd3 = 1e30f;
    int   bj0 = 0x7fffffff, bj1 = 0x7fffffff, bj2 = 0x7fffffff, bj3 = 0x7fffffff;

    if (i < n) {
        const float pix = obs2[2 * i];
        const float piy = obs2[2 * i + 1];
        for (int j = sub; j < n; j += 16) {
            float dx = obs2[2 * j]     - pix;
            float dy = obs2[2 * j + 1] - piy;
            float d2 = __fadd_rn(__fmul_rn(dx, dx), __fmul_rn(dy, dy));
            float dist = __fsqrt_rn(d2);
            if (j == i) continue;
            INS4(dist, j);
        }
    }
    sMd[ii][sub * 4 + 0] = bd0;  sMj[ii][sub * 4 + 0] = bj0;
    sMd[ii][sub * 4 + 1] = bd1;  sMj[ii][sub * 4 + 1] = bj1;
    sMd[ii][sub * 4 + 2] = bd2;  sMj[ii][sub * 4 + 2] = bj2;
    sMd[ii][sub * 4 + 3] = bd3;  sMj[ii][sub * 4 + 3] = bj3;
    __syncthreads();

    if (t < 16) {
        const int r = t;
        const int irow = i0 + r;
        float bd0 = 1e30f, bd1 = 1e30f, bd2 = 1e30f, bd3 = 1e30f;
        int   bj0 = 0x7fffffff, bj1 = 0x7fffffff, bj2 = 0x7fffffff, bj3 = 0x7fffffff;
        for (int q = 0; q < 64; q++) { INS4(sMd[r][q], sMj[r][q]); }

        if (irow < n) {
            float pix = obs2[2 * irow], piy = obs2[2 * irow + 1];
            float vix = pix - obs1[2 * irow];
            float viy = piy - obs1[2 * irow + 1];
            #pragma unroll
            for (int q2 = 0; q2 < 4; q2++) {
                int jn = (q2 == 0) ? bj0 : (q2 == 1) ? bj1 : (q2 == 2) ? bj2 : bj3;
                if (jn < 0 || jn >= n) jn = 0;
                float pjx = obs2[2 * jn], pjy = obs2[2 * jn + 1];
                float px = pjx - pix, py = pjy - piy;
                float vx = (pjx - obs1[2 * jn])     - vix;
                float vy = (pjy - obs1[2 * jn + 1]) - viy;
                #pragma unroll
                for (int e = 0; e < 8; e++) {
                    float a = px * Wemb[e]      + py * Wemb[8 + e]
                            + vx * Wemb[16 + e] + vy * Wemb[24 + e]
                            + bemb[e];
                    sX[r][q2 * 8 + e] = fmaxf(a, 0.0f);
                }
            }
        } else {
            for (int e = 0; e < 32; e++) sX[r][e] = 0.0f;
        }
    }
    __syncthreads();

    const int uu = t;
    float acc[4][16];
    #pragma unroll
    for (int j = 0; j < 4; j++) {
        float b = bih[uu + 256 * j] + bhh[uu + 256 * j];
        #pragma unroll
        for (int r = 0; r < 16; r++) acc[j][r] = b;
    }

    for (int kc = 0; kc < 288; kc++) {
        float w[4];
        #pragma unroll
        for (int j = 0; j < 4; j++) {
            int g = uu + 256 * j;
            w[j] = (kc < 32) ? Wih[(size_t)g * 32 + kc]
                             : Whh[(size_t)g * 256 + (kc - 32)];
        }
        #pragma unroll
        for (int r = 0; r < 16; r++) {
            float x = sX[r][kc];
            #pragma unroll
            for (int j = 0; j < 4; j++) acc[j][r] += w[j] * x;
        }
    }

    for (int r = 0; r < 16; r++) {
        int row = i0 + r;
        float cin = (row < n) ? c[(size_t)row * 256 + uu] : 0.0f;
        float cn = sigf(acc[1][r]) * cin + sigf(acc[0][r]) * tanhf(acc[2][r]);
        float hn = sigf(acc[3][r]) * tanhf(cn);
        sH[r][uu] = hn;
    }
    __syncthreads();

    for (int v = t; v < 16 * 32; v += 256) {
        int r = v >> 5, o = v & 31;
        int row = i0 + r;
        if (row >= n) continue;
        float a = bp[o];
        for (int kc = 0; kc < 256; kc++)
            a += Wp[(size_t)o * 256 + kc] * sH[r][kc];
        out[(size_t)row * 32 + o] = a;
    }
}

extern "C" void kernel_launch(void* const* d_in, const int* in_sizes, int n_in,
                              void* d_out, int out_size, void* d_ws, size_t ws_size,
                              hipStream_t stream) {
    float* out = (float*)d_out;

    int code = 0, n = 0;
    if (n_in != 12) code = 1;
    else {
        n = in_sizes[1] / 2;
        if (n <= 4 || in_sizes[1] != 2 * n)          code = 2;
        else if (in_sizes[0]  != 2 * n)              code = 3;
        else if (in_sizes[2]  != 256 * n)            code = 4;
        else if (in_sizes[3]  != 256 * n)            code = 5;
        else if (in_sizes[4]  != 32 || in_sizes[5] != 8)        code = 6;
        else if (in_sizes[6]  != 32768 || in_sizes[7] != 1024)  code = 7;
        else if (in_sizes[8]  != 262144 || in_sizes[9] != 1024) code = 8;
        else if (in_sizes[10] != 8192 || in_sizes[11] != 32)    code = 9;
        else if (out_size != 32 * n)                 code = 10;
    }
    if (code != 0) {
        diag_kernel<<<1, 1, 0, stream>>>(out, code, out_size);
        return;
    }

    const float* obs1   = (const float*)d_in[0];
    const float* obs2   = (const float*)d_in[1];
    const float* h      = (const float*)d_in[2];
    const float* c      = (const float*)d_in[3];
    const float* W_emb  = (const float*)d_in[4];
    const float* b_emb  = (const float*)d_in[5];
    const float* W_ih   = (const float*)d_in[6];
    const float* b_ih   = (const float*)d_in[7];
    const float* W_hh   = (const float*)d_in[8];
    const float* b_hh   = (const float*)d_in[9];
    const float* W_pool = (const float*)d_in[10];
    const float* b_pool = (const float*)d_in[11];

    const size_t wgf_bytes = (size_t)36864 * 8 * sizeof(u16);   // 589,824
    const size_t wpf_bytes = (size_t)1024 * 8 * sizeof(u16);    //  16,384

    if (ws_size >= wgf_bytes + wpf_bytes && n <= (1 << 24)) {
        u16* Wgf = (u16*)d_ws;
        u16* Wpf = (u16*)((char*)d_ws + wgf_bytes);
        int knn_blocks = (n + 3) / 4;
        knn_prep_kernel<<<knn_blocks + 148, 256, 0, stream>>>(
            obs1, obs2, W_emb, b_emb, W_ih, W_hh, W_pool, Wgf, Wpf,
            n, knn_blocks, out);
        lstm_kernel<<<(n + 15) / 16, 256, 0, stream>>>(
            h, c, Wgf, b_ih, b_hh, Wpf, b_pool, n, out);
    } else {
        nnlstm_fallback<<<(n + 15) / 16, 256, 0, stream>>>(
            obs1, obs2, h, c, W_emb, b_emb, W_ih, b_ih, W_hh, b_hh,
            W_pool, b_pool, n, out);
    }
}

// Round 11
// 153.140 us; speedup vs baseline: 1.3541x; 1.0383x over previous
//
#include <hip/hip_runtime.h>
#include <math.h>

typedef unsigned short u16;
typedef unsigned long long u64;
typedef __attribute__((ext_vector_type(8))) short bf16x8;
typedef __attribute__((ext_vector_type(4))) float f32x4;

__device__ __forceinline__ float sigf(float x)  { return 1.0f / (1.0f + __expf(-x)); }
__device__ __forceinline__ float tanhf_(float x){ float e = __expf(2.0f * x); return 1.0f - 2.0f / (e + 1.0f); }
__device__ __forceinline__ u16 f2bf(float f) {
    unsigned x = __float_as_uint(f);
    return (u16)((x + 0x7fffu + ((x >> 16) & 1u)) >> 16);
}

// u64-key sorted insert: keys k0<=k1<=k2<=k3, key = (asuint(dist)<<24)|idx.
// Single u64 compare == lexicographic (dist, idx) — exactly jax.lax.top_k order.
#define INSU(KEY) do {                                                              \
    u64 _k = (KEY);                                                                 \
    k3 = (_k < k3) ? _k : k3;                                                       \
    { bool _c = k3 < k2; u64 _lo = _c ? k3 : k2, _hi = _c ? k2 : k3; k2 = _lo; k3 = _hi; } \
    { bool _c = k2 < k1; u64 _lo = _c ? k2 : k1, _hi = _c ? k1 : k2; k1 = _lo; k2 = _hi; } \
    { bool _c = k1 < k0; u64 _lo = _c ? k1 : k0, _hi = _c ? k0 : k1; k0 = _lo; k1 = _hi; } \
} while (0)

// float-key variant for the fallback kernel (round-5 proven path)
#define INS4(D, J) do {                                                              \
    float _d = (D); int _j = (J);                                                    \
    if (_d < bd3 || (_d == bd3 && _j < bj3)) {                                       \
        bd3 = _d; bj3 = _j;                                                          \
        if (bd3 < bd2 || (bd3 == bd2 && bj3 < bj2)) {                                \
            float _t = bd2; bd2 = bd3; bd3 = _t; int _u = bj2; bj2 = bj3; bj3 = _u; }\
        if (bd2 < bd1 || (bd2 == bd1 && bj2 < bj1)) {                                \
            float _t = bd1; bd1 = bd2; bd2 = _t; int _u = bj1; bj1 = bj2; bj2 = _u; }\
        if (bd1 < bd0 || (bd1 == bd0 && bj1 < bj0)) {                                \
            float _t = bd0; bd0 = bd1; bd1 = _t; int _u = bj0; bj0 = bj1; bj1 = _u; }\
    } } while (0)

__global__ void diag_kernel(float* out, int code, int out_size) {
    if (out_size > 0) out[0] = (float)code * 1.0e8f;
}

// K1: unchanged from round 10 (proven, VALU-issue-bound at ~56 us).
__global__ __launch_bounds__(256) void knn_prep_kernel(
    const float* __restrict__ obs1, const float* __restrict__ obs2,
    const float* __restrict__ Wemb, const float* __restrict__ bemb,
    const float* __restrict__ Wih,  const float* __restrict__ Whh,
    const float* __restrict__ Wp,
    u16* __restrict__ Wgf, u16* __restrict__ Wpf,
    int n, int knn_blocks, float* __restrict__ out)
{
    const int t = threadIdx.x;

    if (blockIdx.x >= knn_blocks) {
        int id = (blockIdx.x - knn_blocks) * 256 + t;
        if (id < 36864) {                        // gates: 64 gt * 9 kt * 64 lanes
            int gt = id / 576, rem = id - gt * 576;
            int kt = rem >> 6, ln = rem & 63;
            int g  = gt * 16 + (ln & 15);
            int k  = kt * 32 + (ln >> 4) * 8;
            u16* dst = Wgf + (size_t)id * 8;
            #pragma unroll
            for (int j = 0; j < 8; j++) {
                int kk = k + j;
                float v = (kk < 32) ? Wih[(size_t)g * 32 + kk]
                                    : Whh[(size_t)g * 256 + (kk - 32)];
                dst[j] = f2bf(v);
            }
        } else if (id < 37888) {                 // pool: 2 pt * 8 kt * 64 lanes
            int id2 = id - 36864;
            int pt = id2 >> 9, rem = id2 & 511;
            int kt = rem >> 6, ln = rem & 63;
            int o  = pt * 16 + (ln & 15);
            int k  = kt * 32 + (ln >> 4) * 8;
            u16* dst = Wpf + (size_t)id2 * 8;
            #pragma unroll
            for (int j = 0; j < 8; j++)
                dst[j] = f2bf(Wp[(size_t)o * 256 + k + j]);
        }
        return;
    }

    const int lane = t & 63;
    const int wv   = t >> 6;
    const int i    = blockIdx.x * 4 + wv;
    if (i >= n) return;

    const float2* o2 = (const float2*)obs2;
    const float2 pi = o2[i];

    u64 k0 = ~0ull, k1 = ~0ull, k2 = ~0ull, k3 = ~0ull;

    int j = lane;
    for (; j + 192 < n; j += 256) {
        float2 p0 = o2[j], p1 = o2[j + 64], p2 = o2[j + 128], p3 = o2[j + 192];
        float dx, dy, d2, dd; u64 key;
        dx = p0.x - pi.x; dy = p0.y - pi.y;
        d2 = __fadd_rn(__fmul_rn(dx, dx), __fmul_rn(dy, dy));
        dd = __fsqrt_rn(d2);
        key = (((u64)__float_as_uint(dd)) << 24) | (unsigned)j;
        key = (j == i) ? ~0ull : key;                         INSU(key);
        dx = p1.x - pi.x; dy = p1.y - pi.y;
        d2 = __fadd_rn(__fmul_rn(dx, dx), __fmul_rn(dy, dy));
        dd = __fsqrt_rn(d2);
        key = (((u64)__float_as_uint(dd)) << 24) | (unsigned)(j + 64);
        key = (j + 64 == i) ? ~0ull : key;                    INSU(key);
        dx = p2.x - pi.x; dy = p2.y - pi.y;
        d2 = __fadd_rn(__fmul_rn(dx, dx), __fmul_rn(dy, dy));
        dd = __fsqrt_rn(d2);
        key = (((u64)__float_as_uint(dd)) << 24) | (unsigned)(j + 128);
        key = (j + 128 == i) ? ~0ull : key;                   INSU(key);
        dx = p3.x - pi.x; dy = p3.y - pi.y;
        d2 = __fadd_rn(__fmul_rn(dx, dx), __fmul_rn(dy, dy));
        dd = __fsqrt_rn(d2);
        key = (((u64)__float_as_uint(dd)) << 24) | (unsigned)(j + 192);
        key = (j + 192 == i) ? ~0ull : key;                   INSU(key);
    }
    for (; j < n; j += 64) {
        float2 pj = o2[j];
        float dx = pj.x - pi.x, dy = pj.y - pi.y;
        float d2 = __fadd_rn(__fmul_rn(dx, dx), __fmul_rn(dy, dy));
        float dd = __fsqrt_rn(d2);
        u64 key = (((u64)__float_as_uint(dd)) << 24) | (unsigned)j;
        key = (j == i) ? ~0ull : key;
        INSU(key);
    }

    #pragma unroll
    for (int m = 1; m < 64; m <<= 1) {
        u64 o0 = __shfl_xor(k0, m), o1 = __shfl_xor(k1, m);
        u64 o2_ = __shfl_xor(k2, m), o3 = __shfl_xor(k3, m);
        INSU(o0); INSU(o1); INSU(o2_); INSU(o3);
    }

    if (lane < 4) {
        u64 kq = (lane == 0) ? k0 : (lane == 1) ? k1 : (lane == 2) ? k2 : k3;
        int jn = (int)(kq & 0xFFFFFF);
        if (jn < 0 || jn >= n) jn = 0;
        float pix = pi.x, piy = pi.y;
        float pjx = obs2[2 * jn], pjy = obs2[2 * jn + 1];
        float px = pjx - pix, py = pjy - piy;
        float vix = pix - obs1[2 * i];
        float viy = piy - obs1[2 * i + 1];
        float vx = (pjx - obs1[2 * jn])     - vix;
        float vy = (pjy - obs1[2 * jn + 1]) - viy;
        float* dst = out + (size_t)i * 32 + lane * 8;
        #pragma unroll
        for (int e = 0; e < 8; e++) {
            float a = px * Wemb[e]      + py * Wemb[8 + e]
                    + vx * Wemb[16 + e] + vy * Wemb[24 + e]
                    + bemb[e];
            dst[e] = fmaxf(a, 0.0f);
        }
    }
}

// K2 (restructured): 512 threads = 8 waves, 16-row tile, 12 waves/CU.
// Wave wv owns hidden units [wv*32, wv*32+32) (unit-tiles ut = wv*2, wv*2+1).
// Per unit-tile: 4 gate-type MFMA accumulations (i,f,g,o) kept in registers ->
// LSTM pointwise in-lane (lane fm = unit, acc reg r_ = row) -> sHb -> pool MFMA.
// LDS: sXb u16[16][296] (9472 B) + sHb u16[16][264] (8448 B) = 17,920 B.
__global__ __launch_bounds__(512) void lstm_kernel(
    const float* __restrict__ h,   const float* __restrict__ c,
    const u16*  __restrict__ Wgf,  const float* __restrict__ bih,
    const float* __restrict__ bhh,
    const u16*  __restrict__ Wpf,  const float* __restrict__ bp,
    int n, float* __restrict__ out)
{
    __shared__ __align__(16) char lds[17920];
    u16* sXb = (u16*)lds;                     // [16][296] bf16 X=[emb|h]
    u16* sHb = (u16*)(lds + 9472);            // [16][264] bf16 h_new

    const int t    = threadIdx.x;             // 0..511
    const int i0   = blockIdx.x * 16;
    const int lane = t & 63;
    const int wv   = t >> 6;                  // wave 0..7
    const int fm   = lane & 15;
    const int fq   = lane >> 4;

    // stage emb (fp32 in out) -> sXb[:,0:32): 512 floats, one per thread
    {
        int r = t >> 5, e = t & 31;
        int row = i0 + r;
        float v = (row < n) ? out[(size_t)row * 32 + e] : 0.0f;
        sXb[r * 296 + e] = f2bf(v);
    }
    // stage h -> sXb[:,32:288): 1024 float4, 2 per thread
    #pragma unroll
    for (int f = t; f < 16 * 64; f += 512) {
        int r = f >> 6, k4 = f & 63;
        int row = i0 + r;
        float4 hv = (row < n) ? ((const float4*)h)[(size_t)row * 64 + k4]
                              : make_float4(0.f, 0.f, 0.f, 0.f);
        u16* d = &sXb[r * 296 + 32 + k4 * 4];
        d[0] = f2bf(hv.x); d[1] = f2bf(hv.y); d[2] = f2bf(hv.z); d[3] = f2bf(hv.w);
    }
    __syncthreads();

    // A-frags: lane holds X[row=fm][kt*32 + fq*8 + j]
    bf16x8 afr[9];
    #pragma unroll
    for (int kt = 0; kt < 9; kt++)
        afr[kt] = *(const bf16x8*)&sXb[fm * 296 + kt * 32 + fq * 8];

    // gates + pointwise, 2 unit-tiles per wave
    #pragma unroll
    for (int ut2 = 0; ut2 < 2; ut2++) {
        const int ut = wv * 2 + ut2;          // unit tile 0..15
        const int u  = ut * 16 + fm;          // hidden unit this lane owns

        f32x4 acc[4];
        #pragma unroll
        for (int jg = 0; jg < 4; jg++) acc[jg] = (f32x4){0.f, 0.f, 0.f, 0.f};

        #pragma unroll
        for (int jg = 0; jg < 4; jg++) {      // gate type i,f,g,o
            const int gt = jg * 16 + ut;      // tile over gates g = jg*256 + u
            const u16* wbase = Wgf + ((size_t)gt * 9) * 512 + lane * 8;
            #pragma unroll
            for (int kt = 0; kt < 9; kt++) {
                bf16x8 bfr = *(const bf16x8*)(wbase + kt * 512);  // coalesced 1 KB
                acc[jg] = __builtin_amdgcn_mfma_f32_16x16x32_bf16(afr[kt], bfr, acc[jg], 0, 0, 0);
            }
        }

        float b0 = bih[u]       + bhh[u];
        float b1 = bih[u + 256] + bhh[u + 256];
        float b2 = bih[u + 512] + bhh[u + 512];
        float b3 = bih[u + 768] + bhh[u + 768];

        #pragma unroll
        for (int r_ = 0; r_ < 4; r_++) {      // D-layout: row = fq*4 + r_
            int row = i0 + fq * 4 + r_;
            float cin = (row < n) ? c[(size_t)row * 256 + u] : 0.0f;
            float gi = acc[0][r_] + b0;
            float gf = acc[1][r_] + b1;
            float gg = acc[2][r_] + b2;
            float go = acc[3][r_] + b3;
            float cn = sigf(gf) * cin + sigf(gi) * tanhf_(gg);
            float hn = sigf(go) * tanhf_(cn);
            sHb[(fq * 4 + r_) * 264 + u] = f2bf(hn);
        }
    }
    __syncthreads();

    // pool GEMM via MFMA: M=16 x N=32 x K=256; waves 0,1 take one n-tile each
    if (wv < 2) {
        bf16x8 ah[8];
        #pragma unroll
        for (int kt = 0; kt < 8; kt++)
            ah[kt] = *(const bf16x8*)&sHb[fm * 264 + kt * 32 + fq * 8];
        const u16* wbase = Wpf + ((size_t)wv * 8) * 512 + lane * 8;
        f32x4 acc = {0.f, 0.f, 0.f, 0.f};
        #pragma unroll
        for (int kt = 0; kt < 8; kt++) {
            bf16x8 bfr = *(const bf16x8*)(wbase + kt * 512);
            acc = __builtin_amdgcn_mfma_f32_16x16x32_bf16(ah[kt], bfr, acc, 0, 0, 0);
        }
        float bias = bp[wv * 16 + fm];
        #pragma unroll
        for (int r_ = 0; r_ < 4; r_++) {
            int row = i0 + fq * 4 + r_;
            if (row < n) out[(size_t)row * 32 + wv * 16 + fm] = acc[r_] + bias;
        }
    }
}

// ---- proven round-5 fallback (only if ws too small) ----
__global__ __launch_bounds__(256) void nnlstm_fallback(
    const float* __restrict__ obs1, const float* __restrict__ obs2,
    const float* __restrict__ h,    const float* __restrict__ c,
    const float* __restrict__ Wemb, const float* __restrict__ bemb,
    const float* __restrict__ Wih,  const float* __restrict__ bih,
    const float* __restrict__ Whh,  const float* __restrict__ bhh,
    const float* __restrict__ Wp,   const float* __restrict__ bp,
    int n, float* __restrict__ out)
{
    __shared__ float sMd[16][64];
    __shared__ int   sMj[16][64];
    __shared__ float sX[16][292];
    __shared__ float sH[16][264];

    const int t   = threadIdx.x;
    const int sub = t & 15;
    const int ii  = t >> 4;
    const int i0  = blockIdx.x * 16;
    const int i   = i0 + ii;

    for (int v = t; v < 16 * 256; v += 256) {
        int r = v >> 8, k = v & 255;
        int row = i0 + r;
        sX[r][32 + k] = (row < n) ? h[(size_t)row * 256 + k] : 0.0f;
    }

    float bd0 = 1e30f, bd1 = 1e30f, bd2 = 1e30f, bd3 = 1e30f;
    int   bj0 = 0x7fffffff, bj1 = 0x7fffffff, bj2 = 0x7fffffff, bj3 = 0x7fffffff;

    if (i < n) {
        const float pix = obs2[2 * i];
        const float piy = obs2[2 * i + 1];
        for (int j = sub; j < n; j += 16) {
            float dx = obs2[2 * j]     - pix;
            float dy = obs2[2 * j + 1] - piy;
            float d2 = __fadd_rn(__fmul_rn(dx, dx), __fmul_rn(dy, dy));
            float dist = __fsqrt_rn(d2);
            if (j == i) continue;
            INS4(dist, j);
        }
    }
    sMd[ii][sub * 4 + 0] = bd0;  sMj[ii][sub * 4 + 0] = bj0;
    sMd[ii][sub * 4 + 1] = bd1;  sMj[ii][sub * 4 + 1] = bj1;
    sMd[ii][sub * 4 + 2] = bd2;  sMj[ii][sub * 4 + 2] = bj2;
    sMd[ii][sub * 4 + 3] = bd3;  sMj[ii][sub * 4 + 3] = bj3;
    __syncthreads();

    if (t < 16) {
        const int r = t;
        const int irow = i0 + r;
        float bd0 = 1e30f, bd1 = 1e30f, bd2 = 1e30f, bd3 = 1e30f;
        int   bj0 = 0x7fffffff, bj1 = 0x7fffffff, bj2 = 0x7fffffff, bj3 = 0x7fffffff;
        for (int q = 0; q < 64; q++) { INS4(sMd[r][q], sMj[r][q]); }

        if (irow < n) {
            float pix = obs2[2 * irow], piy = obs2[2 * irow + 1];
            float vix = pix - obs1[2 * irow];
            float viy = piy - obs1[2 * irow + 1];
            #pragma unroll
            for (int q2 = 0; q2 < 4; q2++) {
                int jn = (q2 == 0) ? bj0 : (q2 == 1) ? bj1 : (q2 == 2) ? bj2 : bj3;
                if (jn < 0 || jn >= n) jn = 0;
                float pjx = obs2[2 * jn], pjy = obs2[2 * jn + 1];
                float px = pjx - pix, py = pjy - piy;
                float vx = (pjx - obs1[2 * jn])     - vix;
                float vy = (pjy - obs1[2 * jn + 1]) - viy;
                #pragma unroll
                for (int e = 0; e < 8; e++) {
                    float a = px * Wemb[e]      + py * Wemb[8 + e]
                            + vx * Wemb[16 + e] + vy * Wemb[24 + e]
                            + bemb[e];
                    sX[r][q2 * 8 + e] = fmaxf(a, 0.0f);
                }
            }
        } else {
            for (int e = 0; e < 32; e++) sX[r][e] = 0.0f;
        }
    }
    __syncthreads();

    const int uu = t;
    float acc[4][16];
    #pragma unroll
    for (int j = 0; j < 4; j++) {
        float b = bih[uu + 256 * j] + bhh[uu + 256 * j];
        #pragma unroll
        for (int r = 0; r < 16; r++) acc[j][r] = b;
    }

    for (int kc = 0; kc < 288; kc++) {
        float w[4];
        #pragma unroll
        for (int j = 0; j < 4; j++) {
            int g = uu + 256 * j;
            w[j] = (kc < 32) ? Wih[(size_t)g * 32 + kc]
                             : Whh[(size_t)g * 256 + (kc - 32)];
        }
        #pragma unroll
        for (int r = 0; r < 16; r++) {
            float x = sX[r][kc];
            #pragma unroll
            for (int j = 0; j < 4; j++) acc[j][r] += w[j] * x;
        }
    }

    for (int r = 0; r < 16; r++) {
        int row = i0 + r;
        float cin = (row < n) ? c[(size_t)row * 256 + uu] : 0.0f;
        float cn = sigf(acc[1][r]) * cin + sigf(acc[0][r]) * tanhf(acc[2][r]);
        float hn = sigf(acc[3][r]) * tanhf(cn);
        sH[r][uu] = hn;
    }
    __syncthreads();

    for (int v = t; v < 16 * 32; v += 256) {
        int r = v >> 5, o = v & 31;
        int row = i0 + r;
        if (row >= n) continue;
        float a = bp[o];
        for (int kc = 0; kc < 256; kc++)
            a += Wp[(size_t)o * 256 + kc] * sH[r][kc];
        out[(size_t)row * 32 + o] = a;
    }
}

extern "C" void kernel_launch(void* const* d_in, const int* in_sizes, int n_in,
                              void* d_out, int out_size, void* d_ws, size_t ws_size,
                              hipStream_t stream) {
    float* out = (float*)d_out;

    int code = 0, n = 0;
    if (n_in != 12) code = 1;
    else {
        n = in_sizes[1] / 2;
        if (n <= 4 || in_sizes[1] != 2 * n)          code = 2;
        else if (in_sizes[0]  != 2 * n)              code = 3;
        else if (in_sizes[2]  != 256 * n)            code = 4;
        else if (in_sizes[3]  != 256 * n)            code = 5;
        else if (in_sizes[4]  != 32 || in_sizes[5] != 8)        code = 6;
        else if (in_sizes[6]  != 32768 || in_sizes[7] != 1024)  code = 7;
        else if (in_sizes[8]  != 262144 || in_sizes[9] != 1024) code = 8;
        else if (in_sizes[10] != 8192 || in_sizes[11] != 32)    code = 9;
        else if (out_size != 32 * n)                 code = 10;
    }
    if (code != 0) {
        diag_kernel<<<1, 1, 0, stream>>>(out, code, out_size);
        return;
    }

    const float* obs1   = (const float*)d_in[0];
    const float* obs2   = (const float*)d_in[1];
    const float* h      = (const float*)d_in[2];
    const float* c      = (const float*)d_in[3];
    const float* W_emb  = (const float*)d_in[4];
    const float* b_emb  = (const float*)d_in[5];
    const float* W_ih   = (const float*)d_in[6];
    const float* b_ih   = (const float*)d_in[7];
    const float* W_hh   = (const float*)d_in[8];
    const float* b_hh   = (const float*)d_in[9];
    const float* W_pool = (const float*)d_in[10];
    const float* b_pool = (const float*)d_in[11];

    const size_t wgf_bytes = (size_t)36864 * 8 * sizeof(u16);   // 589,824
    const size_t wpf_bytes = (size_t)1024 * 8 * sizeof(u16);    //  16,384

    if (ws_size >= wgf_bytes + wpf_bytes && n <= (1 << 24)) {
        u16* Wgf = (u16*)d_ws;
        u16* Wpf = (u16*)((char*)d_ws + wgf_bytes);
        int knn_blocks = (n + 3) / 4;
        knn_prep_kernel<<<knn_blocks + 148, 256, 0, stream>>>(
            obs1, obs2, W_emb, b_emb, W_ih, W_hh, W_pool, Wgf, Wpf,
            n, knn_blocks, out);
        lstm_kernel<<<(n + 15) / 16, 512, 0, stream>>>(
            h, c, Wgf, b_ih, b_hh, Wpf, b_pool, n, out);
    } else {
        nnlstm_fallback<<<(n + 15) / 16, 256, 0, stream>>>(
            obs1, obs2, h, c, W_emb, b_emb, W_ih, b_ih, W_hh, b_hh,
            W_pool, b_pool, n, out);
    }
}